// Round 6
// baseline (415.017 us; speedup 1.0000x reference)
//
#include <hip/hip_runtime.h>

#define ALG_DIM 248
#define ROWS 32                    // rows per main-kernel block (bf16: 8 rows/lane)
#define KSPLIT 4
#define KPB 62                     // k-slots per block (248/4)
#define PMAX 1024                  // safety clamp for padded bucket length

// ---------- prep: bucket triples by idx_k into SIZE-SORTED padded slots ----------
// Identical to round 5. Slot p (sorted by size desc) holds bucket perm[p].
// Index halves pre-scaled to LDS byte offsets: lo16 = i*64, hi16 = j*64
// (64 B = column stride = 32 rows x 2 B bf16).

__global__ void k_init(int* __restrict__ cnt) {
    int t = threadIdx.x;
    if (t < ALG_DIM) cnt[t] = 0;
}

__global__ void k_count(const int* __restrict__ idx_k, int* __restrict__ cnt, int nnz) {
    int t = blockIdx.x * blockDim.x + threadIdx.x;
    if (t < nnz) atomicAdd(&cnt[idx_k[t]], 1);
}

__global__ void k_sort(const int* __restrict__ cnt, int* __restrict__ meta,
                       int* __restrict__ perm, int* __restrict__ ssz,
                       int* __restrict__ cursor, int* __restrict__ bbase) {
    __shared__ int sz[256];
    __shared__ int red[256];
    const int t = threadIdx.x;
    sz[t] = (t < ALG_DIM) ? cnt[t] : 0;
    __syncthreads();
    red[t] = sz[t];
    __syncthreads();
    for (int off = 128; off > 0; off >>= 1) {
        if (t < off) red[t] = max(red[t], red[t + off]);
        __syncthreads();
    }
    __shared__ int Ps;
    if (t == 0) {
        int P = (red[0] + 7) & ~7;
        P = max(P, 8);
        P = min(P, PMAX);
        meta[0] = P;
        Ps = P;
    }
    __syncthreads();
    if (t < ALG_DIM) {
        const int mysz = sz[t];
        int rank = 0;
        for (int k = 0; k < ALG_DIM; ++k) {
            int s2 = sz[k];
            rank += (s2 > mysz) || (s2 == mysz && k < t);
        }
        perm[rank] = t;
        ssz[rank]  = mysz;
        cursor[t]  = rank * Ps;
        bbase[t]   = rank * Ps;
    }
}

__global__ void k_fill(uint2* __restrict__ packedP, const int* __restrict__ meta) {
    int P = meta[0];
    int total = ALG_DIM * P + 8;
    int stride = gridDim.x * blockDim.x;
    for (int t = blockIdx.x * blockDim.x + threadIdx.x; t < total; t += stride)
        packedP[t] = make_uint2(0u, 0u);
}

__global__ void k_scatter(const int* __restrict__ idx_i, const int* __restrict__ idx_j,
                          const int* __restrict__ idx_k, const float* __restrict__ coeff,
                          int* __restrict__ cursor, const int* __restrict__ bbase,
                          uint2* __restrict__ packedP, const int* __restrict__ meta,
                          int nnz) {
    int t = blockIdx.x * blockDim.x + threadIdx.x;
    if (t < nnz) {
        int k = idx_k[t];
        int P = meta[0];
        int pos = atomicAdd(&cursor[k], 1);
        if (pos < bbase[k] + P) {
            uint2 p;
            p.x = ((unsigned)idx_i[t] << 6) | ((unsigned)idx_j[t] << 22);
            p.y = __float_as_uint(coeff[t]);
            packedP[pos] = p;
        }
    }
}

// ---------- main: bf16-LDS sorted-slot gather-multiply-accumulate ----------
// 256 threads = 64 streams x 4 lanes over 32 rows x 62 slots. LDS holds x,y
// as bf16 column-major: element (col i, row r) at byte i*64 + r*2 (31 KB
// total -> 5 blocks/CU). A lane's ds_read_b128 = 8 rows of one column, so
// one wave-triple needs only 2 b128 for 32 rows — HALF of round 5's LDS
// instruction count, which was the measured bottleneck (~12 cyc/b128).
// Products computed in fp32 after shift/mask unpack; validated threshold
// (1.34) is bf16-grade, est. added error < 0.3.

__device__ __forceinline__ unsigned bf16rne(float f) {
    unsigned u = __float_as_uint(f);
    return (u + 0x7FFFu + ((u >> 16) & 1u)) >> 16;
}
__device__ __forceinline__ unsigned pack2(float lo, float hi) {
    return bf16rne(lo) | (bf16rne(hi) << 16);
}
__device__ __forceinline__ float blo(unsigned w) { return __uint_as_float(w << 16); }
__device__ __forceinline__ float bhi(unsigned w) { return __uint_as_float(w & 0xFFFF0000u); }

__global__ __launch_bounds__(256, 5) void k_main(
    const float* __restrict__ x, const float* __restrict__ y,
    const uint4* __restrict__ packed4,
    const int* __restrict__ meta, const int* __restrict__ perm,
    const int* __restrict__ ssz,
    const float* __restrict__ alpha_p, float* __restrict__ out)
{
    __shared__ __align__(16) unsigned short xs[ALG_DIM * ROWS];
    __shared__ __align__(16) unsigned short ys[ALG_DIM * ROWS];
    unsigned* xs32 = reinterpret_cast<unsigned*>(xs);
    unsigned* ys32 = reinterpret_cast<unsigned*>(ys);

    const int tid = threadIdx.x;
    const int r0  = blockIdx.x * ROWS;

    // Staging: unit = (row-pair rp, col-quad cq). Lane reads float4 along rows
    // 2rp and 2rp+1, packs bf16 pairs, writes 4 ds_write_b32. rp is the FAST
    // index -> per store instr bank = (16m + rp) % 32: 4-way (free-ish, tiny).
    for (int u = tid; u < (ALG_DIM / 4) * (ROWS / 2); u += 256) {
        const int rp = u & 15;
        const int cq = u >> 4;                 // 0..61
        const size_t ra = (size_t)(r0 + 2 * rp) * ALG_DIM + 4 * cq;
        const float4 xa = *reinterpret_cast<const float4*>(x + ra);
        const float4 xb = *reinterpret_cast<const float4*>(x + ra + ALG_DIM);
        const float4 ya = *reinterpret_cast<const float4*>(y + ra);
        const float4 yb = *reinterpret_cast<const float4*>(y + ra + ALG_DIM);
        const int e = (4 * cq) * (ROWS / 2) + rp;   // uint element index
        xs32[e]                  = pack2(xa.x, xb.x);
        xs32[e + (ROWS / 2)]     = pack2(xa.y, xb.y);
        xs32[e + 2 * (ROWS / 2)] = pack2(xa.z, xb.z);
        xs32[e + 3 * (ROWS / 2)] = pack2(xa.w, xb.w);
        ys32[e]                  = pack2(ya.x, yb.x);
        ys32[e + (ROWS / 2)]     = pack2(ya.y, yb.y);
        ys32[e + 2 * (ROWS / 2)] = pack2(ya.z, yb.z);
        ys32[e + 3 * (ROWS / 2)] = pack2(ya.w, yb.w);
    }
    __syncthreads();

    const int   P     = meta[0];
    const float alpha = alpha_p[0];
    const int   S     = tid >> 2;              // stream 0..63 (owns one slot)
    const int   qo    = (tid & 3) << 4;        // lane byte offset: rows 8q..8q+7

    const char* xsb = reinterpret_cast<const char*>(xs) + qo;
    const char* ysb = reinterpret_cast<const char*>(ys) + qo;

    if (S < KPB) {
        const int p = blockIdx.y * KPB + S;
        const int k = perm[p];

        const int pw   = blockIdx.y * KPB + ((tid >> 6) << 4);
        const int trip = __builtin_amdgcn_readfirstlane((ssz[pw] + 7) & ~7);

        const uint4* tp = packed4 + (size_t)p * (P >> 1);

        float a0 = 0.f, a1 = 0.f, a2 = 0.f, a3 = 0.f,
              a4 = 0.f, a5 = 0.f, a6 = 0.f, a7 = 0.f;
        uint4 A = tp[0], B = tp[1], C = tp[2], D = tp[3];   // 8 triples in flight

        for (int t = 0; t < trip; t += 8) {
            const int nb = (t >> 1) + 4;
            uint4 E = tp[nb + 0];
            uint4 F = tp[nb + 1];
            uint4 G = tp[nb + 2];
            uint4 H = tp[nb + 3];

#define BODY(PW, PC)                                                            \
            {                                                                   \
                const uint4 wx = *reinterpret_cast<const uint4*>(xsb + ((PW) & 0xFFFFu)); \
                const uint4 wy = *reinterpret_cast<const uint4*>(ysb + ((PW) >> 16));     \
                const float cc = __uint_as_float(PC);                           \
                a0 = fmaf(blo(wx.x) * blo(wy.x), cc, a0);                       \
                a1 = fmaf(bhi(wx.x) * bhi(wy.x), cc, a1);                       \
                a2 = fmaf(blo(wx.y) * blo(wy.y), cc, a2);                       \
                a3 = fmaf(bhi(wx.y) * bhi(wy.y), cc, a3);                       \
                a4 = fmaf(blo(wx.z) * blo(wy.z), cc, a4);                       \
                a5 = fmaf(bhi(wx.z) * bhi(wy.z), cc, a5);                       \
                a6 = fmaf(blo(wx.w) * blo(wy.w), cc, a6);                       \
                a7 = fmaf(bhi(wx.w) * bhi(wy.w), cc, a7);                       \
            }
            BODY(A.x, A.y) BODY(A.z, A.w)
            BODY(B.x, B.y) BODY(B.z, B.w)
            BODY(C.x, C.y) BODY(C.z, C.w)
            BODY(D.x, D.y) BODY(D.z, D.w)
#undef BODY
            A = E; B = F; C = G; D = H;
        }

        const int rbase = r0 + ((tid & 3) << 3);
        out[(size_t)(rbase + 0) * ALG_DIM + k] = alpha * a0;
        out[(size_t)(rbase + 1) * ALG_DIM + k] = alpha * a1;
        out[(size_t)(rbase + 2) * ALG_DIM + k] = alpha * a2;
        out[(size_t)(rbase + 3) * ALG_DIM + k] = alpha * a3;
        out[(size_t)(rbase + 4) * ALG_DIM + k] = alpha * a4;
        out[(size_t)(rbase + 5) * ALG_DIM + k] = alpha * a5;
        out[(size_t)(rbase + 6) * ALG_DIM + k] = alpha * a6;
        out[(size_t)(rbase + 7) * ALG_DIM + k] = alpha * a7;
    }
}

// ---------- launch ----------

extern "C" void kernel_launch(void* const* d_in, const int* in_sizes, int n_in,
                              void* d_out, int out_size, void* d_ws, size_t ws_size,
                              hipStream_t stream) {
    const float* x      = (const float*)d_in[0];
    const float* y      = (const float*)d_in[1];
    const int*   idx_i  = (const int*)d_in[2];
    const int*   idx_j  = (const int*)d_in[3];
    const int*   idx_k  = (const int*)d_in[4];
    const float* coeff  = (const float*)d_in[5];
    const float* alpha  = (const float*)d_in[6];
    float*       out    = (float*)d_out;

    const int nnz   = in_sizes[2];
    const int batch = in_sizes[0] / ALG_DIM;

    // ws: [meta 16B][cnt 1K][cursor 1K][perm 1K][ssz 1K][bbase 1K][pad->8K][packedP]
    char*  ws      = (char*)d_ws;
    int*   meta    = (int*)ws;
    int*   cnt     = (int*)(ws + 16);
    int*   cursor  = (int*)(ws + 16 + 1024);
    int*   perm    = (int*)(ws + 16 + 2 * 1024);
    int*   ssz     = (int*)(ws + 16 + 3 * 1024);
    int*   bbase   = (int*)(ws + 16 + 4 * 1024);
    uint2* packedP = (uint2*)(ws + 8192);

    k_init   <<<1, 256, 0, stream>>>(cnt);
    k_count  <<<(nnz + 255) / 256, 256, 0, stream>>>(idx_k, cnt, nnz);
    k_sort   <<<1, 256, 0, stream>>>(cnt, meta, perm, ssz, cursor, bbase);
    k_fill   <<<256, 256, 0, stream>>>(packedP, meta);
    k_scatter<<<(nnz + 255) / 256, 256, 0, stream>>>(idx_i, idx_j, idx_k, coeff,
                                                     cursor, bbase, packedP, meta, nnz);

    dim3 grid(batch / ROWS, KSPLIT);
    k_main<<<grid, 256, 0, stream>>>(x, y, (const uint4*)packedP, meta, perm, ssz,
                                     alpha, out);
}

// Round 8
// 151.452 us; speedup vs baseline: 2.7403x; 2.7403x over previous
//
#include <hip/hip_runtime.h>

#define ALG_DIM 248
#define ROWS 32                    // rows per main-kernel block (f16: 8 rows/lane/b128)
#define KSPLIT 4
#define KPB 62                     // k-slots per block (248/4)
#define PMAX 1024                  // safety clamp for padded bucket length

typedef __fp16 h2v __attribute__((ext_vector_type(2)));
union H2U { unsigned u; h2v h; };

// ---------- prep: bucket triples by idx_k into SIZE-SORTED padded slots ----------
// Identical to round 5 (known good). Slot p (sorted by size desc) holds bucket
// perm[p]. Index halves pre-scaled to LDS byte offsets: lo16 = i*64, hi16 = j*64
// (64 B = column stride = 32 rows x 2 B f16). coeff stays fp32.

__global__ void k_init(int* __restrict__ cnt) {
    int t = threadIdx.x;
    if (t < ALG_DIM) cnt[t] = 0;
}

__global__ void k_count(const int* __restrict__ idx_k, int* __restrict__ cnt, int nnz) {
    int t = blockIdx.x * blockDim.x + threadIdx.x;
    if (t < nnz) atomicAdd(&cnt[idx_k[t]], 1);
}

__global__ void k_sort(const int* __restrict__ cnt, int* __restrict__ meta,
                       int* __restrict__ perm, int* __restrict__ ssz,
                       int* __restrict__ cursor, int* __restrict__ bbase) {
    __shared__ int sz[256];
    __shared__ int red[256];
    const int t = threadIdx.x;
    sz[t] = (t < ALG_DIM) ? cnt[t] : 0;
    __syncthreads();
    red[t] = sz[t];
    __syncthreads();
    for (int off = 128; off > 0; off >>= 1) {
        if (t < off) red[t] = max(red[t], red[t + off]);
        __syncthreads();
    }
    __shared__ int Ps;
    if (t == 0) {
        int P = (red[0] + 7) & ~7;
        P = max(P, 8);
        P = min(P, PMAX);
        meta[0] = P;
        Ps = P;
    }
    __syncthreads();
    if (t < ALG_DIM) {
        const int mysz = sz[t];
        int rank = 0;
        for (int k = 0; k < ALG_DIM; ++k) {
            int s2 = sz[k];
            rank += (s2 > mysz) || (s2 == mysz && k < t);
        }
        perm[rank] = t;
        ssz[rank]  = mysz;
        cursor[t]  = rank * Ps;
        bbase[t]   = rank * Ps;
    }
}

__global__ void k_fill(uint2* __restrict__ packedP, const int* __restrict__ meta) {
    int P = meta[0];
    int total = ALG_DIM * P + 8;
    int stride = gridDim.x * blockDim.x;
    for (int t = blockIdx.x * blockDim.x + threadIdx.x; t < total; t += stride)
        packedP[t] = make_uint2(0u, 0u);
}

__global__ void k_scatter(const int* __restrict__ idx_i, const int* __restrict__ idx_j,
                          const int* __restrict__ idx_k, const float* __restrict__ coeff,
                          int* __restrict__ cursor, const int* __restrict__ bbase,
                          uint2* __restrict__ packedP, const int* __restrict__ meta,
                          int nnz) {
    int t = blockIdx.x * blockDim.x + threadIdx.x;
    if (t < nnz) {
        int k = idx_k[t];
        int P = meta[0];
        int pos = atomicAdd(&cursor[k], 1);
        if (pos < bbase[k] + P) {
            uint2 p;
            p.x = ((unsigned)idx_i[t] << 6) | ((unsigned)idx_j[t] << 22);
            p.y = __float_as_uint(coeff[t]);
            packedP[pos] = p;
        }
    }
}

// ---------- main: f16-LDS sorted-slot gather, swizzled banks, lean body ----------
// 256 threads = 64 streams x 4 lanes over 32 rows x 62 slots. x,y in LDS as
// f16, column-major, 64 B/column, with 16 B sub-blocks XOR-swizzled:
//   element (col i, row r) at byte  i*64 + ((r>>3) ^ ((i>>1)&3))*16 + (r&7)*2
// Lane q's gather (rows 8q..8q+7 of col i) = ONE ds_read_b128 at
//   i*64 + (q ^ ((i>>1)&3))*16  -> bank-quad uniform over all 8 groups as i
// varies (kills round-5's parity conflicts, which were ~33% of the LDS pipe).
// Loop body is deliberately tiny (2 triples per iter, 1-deep prefetch,
// unroll 2) so neither we nor the compiler can recreate round-6's spill storm.
// Products v_pk_mul_f16, accumulation fp32.

__global__ __launch_bounds__(256, 4) void k_main(
    const float* __restrict__ x, const float* __restrict__ y,
    const uint4* __restrict__ packed4,
    const int* __restrict__ meta, const int* __restrict__ perm,
    const int* __restrict__ ssz,
    const float* __restrict__ alpha_p, float* __restrict__ out)
{
    __shared__ __align__(16) unsigned xs32[ALG_DIM * ROWS / 2];
    __shared__ __align__(16) unsigned ys32[ALG_DIM * ROWS / 2];

    const int tid = threadIdx.x;
    const int r0  = blockIdx.x * ROWS;

    // Staging: unit u = (row-pair rp 0..15, col-quad cq 0..61). Lane reads
    // float4 along rows 2rp and 2rp+1, packs (even,odd) halves via cvt_pkrtz,
    // writes 4 swizzled ds_write_b32 per array.
    for (int u = tid; u < (ALG_DIM / 4) * (ROWS / 2); u += 256) {
        const int rp = u & 15;
        const int cq = u >> 4;
        const size_t ra = (size_t)(r0 + 2 * rp) * ALG_DIM + 4 * cq;
        const float4 xa = *reinterpret_cast<const float4*>(x + ra);
        const float4 xb = *reinterpret_cast<const float4*>(x + ra + ALG_DIM);
        const float4 ya = *reinterpret_cast<const float4*>(y + ra);
        const float4 yb = *reinterpret_cast<const float4*>(y + ra + ALG_DIM);
        const int s   = rp >> 2;            // sub-block (rows 8s..8s+7)
        const int iw  = rp & 3;             // dword within sub-block
#define STG(d, XA, XB, YA, YB)                                                  \
        {                                                                       \
            const int c = 4 * cq + (d);                                         \
            const int dw = (c * 64 + ((s ^ ((c >> 1) & 3)) * 16)) / 4 + iw;     \
            H2U hx; hx.h = __builtin_amdgcn_cvt_pkrtz(XA, XB);                  \
            H2U hy; hy.h = __builtin_amdgcn_cvt_pkrtz(YA, YB);                  \
            xs32[dw] = hx.u;                                                    \
            ys32[dw] = hy.u;                                                    \
        }
        STG(0, xa.x, xb.x, ya.x, yb.x)
        STG(1, xa.y, xb.y, ya.y, yb.y)
        STG(2, xa.z, xb.z, ya.z, yb.z)
        STG(3, xa.w, xb.w, ya.w, yb.w)
#undef STG
    }
    __syncthreads();

    const int   P     = meta[0];
    const float alpha = alpha_p[0];
    const int   S     = tid >> 2;            // stream 0..63 (owns one slot)
    const int   qo    = (tid & 3) << 4;      // my sub-block byte offset (q*16)

    const char* xsb = reinterpret_cast<const char*>(xs32);
    const char* ysb = reinterpret_cast<const char*>(ys32);

    if (S < KPB) {
        const int p = blockIdx.y * KPB + S;
        const int k = perm[p];

        const int pw   = blockIdx.y * KPB + ((tid >> 6) << 4);
        const int trip = __builtin_amdgcn_readfirstlane((ssz[pw] + 7) & ~7);

        const uint4* tp = packed4 + (size_t)p * (P >> 1);

        float a0 = 0.f, a1 = 0.f, a2 = 0.f, a3 = 0.f,
              a4 = 0.f, a5 = 0.f, a6 = 0.f, a7 = 0.f;

        uint4 cur = tp[0];
        const int nH = trip >> 1;            // uint4s (2 triples each)

#define PROC(PW, PC)                                                            \
        {                                                                       \
            const unsigned ox = (PW) & 0xFFFFu;                                 \
            const unsigned oy = (PW) >> 16;                                     \
            const uint4 wx = *reinterpret_cast<const uint4*>(                   \
                xsb + ox + (qo ^ ((ox >> 3) & 0x30u)));                         \
            const uint4 wy = *reinterpret_cast<const uint4*>(                   \
                ysb + oy + (qo ^ ((oy >> 3) & 0x30u)));                         \
            const float cc = __uint_as_float(PC);                               \
            H2U ux, uy, pr;                                                     \
            ux.u = wx.x; uy.u = wy.x; pr.h = ux.h * uy.h;                       \
            a0 = fmaf((float)pr.h.x, cc, a0);                                   \
            a1 = fmaf((float)pr.h.y, cc, a1);                                   \
            ux.u = wx.y; uy.u = wy.y; pr.h = ux.h * uy.h;                       \
            a2 = fmaf((float)pr.h.x, cc, a2);                                   \
            a3 = fmaf((float)pr.h.y, cc, a3);                                   \
            ux.u = wx.z; uy.u = wy.z; pr.h = ux.h * uy.h;                       \
            a4 = fmaf((float)pr.h.x, cc, a4);                                   \
            a5 = fmaf((float)pr.h.y, cc, a5);                                   \
            ux.u = wx.w; uy.u = wy.w; pr.h = ux.h * uy.h;                       \
            a6 = fmaf((float)pr.h.x, cc, a6);                                   \
            a7 = fmaf((float)pr.h.y, cc, a7);                                   \
        }

#pragma unroll 2
        for (int h = 0; h < nH; ++h) {
            const uint4 nxt = tp[h + 1];     // 1-deep prefetch (slack-padded)
            PROC(cur.x, cur.y)
            PROC(cur.z, cur.w)
            cur = nxt;
        }
#undef PROC

        const int rbase = r0 + ((tid & 3) << 3);
        out[(size_t)(rbase + 0) * ALG_DIM + k] = alpha * a0;
        out[(size_t)(rbase + 1) * ALG_DIM + k] = alpha * a1;
        out[(size_t)(rbase + 2) * ALG_DIM + k] = alpha * a2;
        out[(size_t)(rbase + 3) * ALG_DIM + k] = alpha * a3;
        out[(size_t)(rbase + 4) * ALG_DIM + k] = alpha * a4;
        out[(size_t)(rbase + 5) * ALG_DIM + k] = alpha * a5;
        out[(size_t)(rbase + 6) * ALG_DIM + k] = alpha * a6;
        out[(size_t)(rbase + 7) * ALG_DIM + k] = alpha * a7;
    }
}

// ---------- launch ----------

extern "C" void kernel_launch(void* const* d_in, const int* in_sizes, int n_in,
                              void* d_out, int out_size, void* d_ws, size_t ws_size,
                              hipStream_t stream) {
    const float* x      = (const float*)d_in[0];
    const float* y      = (const float*)d_in[1];
    const int*   idx_i  = (const int*)d_in[2];
    const int*   idx_j  = (const int*)d_in[3];
    const int*   idx_k  = (const int*)d_in[4];
    const float* coeff  = (const float*)d_in[5];
    const float* alpha  = (const float*)d_in[6];
    float*       out    = (float*)d_out;

    const int nnz   = in_sizes[2];
    const int batch = in_sizes[0] / ALG_DIM;

    // ws: [meta 16B][cnt 1K][cursor 1K][perm 1K][ssz 1K][bbase 1K][pad->8K][packedP]
    char*  ws      = (char*)d_ws;
    int*   meta    = (int*)ws;
    int*   cnt     = (int*)(ws + 16);
    int*   cursor  = (int*)(ws + 16 + 1024);
    int*   perm    = (int*)(ws + 16 + 2 * 1024);
    int*   ssz     = (int*)(ws + 16 + 3 * 1024);
    int*   bbase   = (int*)(ws + 16 + 4 * 1024);
    uint2* packedP = (uint2*)(ws + 8192);

    k_init   <<<1, 256, 0, stream>>>(cnt);
    k_count  <<<(nnz + 255) / 256, 256, 0, stream>>>(idx_k, cnt, nnz);
    k_sort   <<<1, 256, 0, stream>>>(cnt, meta, perm, ssz, cursor, bbase);
    k_fill   <<<256, 256, 0, stream>>>(packedP, meta);
    k_scatter<<<(nnz + 255) / 256, 256, 0, stream>>>(idx_i, idx_j, idx_k, coeff,
                                                     cursor, bbase, packedP, meta, nnz);

    dim3 grid(batch / ROWS, KSPLIT);
    k_main<<<grid, 256, 0, stream>>>(x, y, (const uint4*)packedP, meta, perm, ssz,
                                     alpha, out);
}

// Round 9
// 147.224 us; speedup vs baseline: 2.8189x; 1.0287x over previous
//
#include <hip/hip_runtime.h>

#define ALG_DIM 248
#define ROWS 32                    // rows per main-kernel block
#define KSPLIT 4
#define KPB 62                     // k-slots per block (248/4)
#define PMAX 1024                  // safety clamp for padded bucket length
#define PLSTRIDE_B 3984            // plane stride bytes (248*16 + 16; /4 = 996 ≡ 4 mod 32)
#define PLSTRIDE_DW 996

typedef __fp16 h2v __attribute__((ext_vector_type(2)));
union H2U { unsigned u; h2v h; };

// ---------- prep: size-sorted padded slots, pads written by k_sort ----------
// Slot p (sorted desc by size) holds bucket perm[p] at packedP[p*(P+8) ...).
// Real entries [0,size), zero pads [size, trip+8) where trip = round8 of the
// slot's 16-group max (matching k_main's wave-uniform trip + 2-triple
// prefetch over-read). Region [trip+8, P+8) is never read.
// packed.x: lo16 = i*16, hi16 = j*16 (within-plane byte offsets).
// packed.y: coeff as duplicated f16x2 (zero conversion cost in k_main).

__global__ void k_init(int* __restrict__ cnt) {
    int t = threadIdx.x;
    if (t < ALG_DIM) cnt[t] = 0;
}

__global__ void k_count(const int* __restrict__ idx_k, int* __restrict__ cnt, int nnz) {
    int t = blockIdx.x * blockDim.x + threadIdx.x;
    if (t < nnz) atomicAdd(&cnt[idx_k[t]], 1);
}

__global__ void k_sort(const int* __restrict__ cnt, int* __restrict__ meta,
                       int* __restrict__ perm, int* __restrict__ ssz,
                       int* __restrict__ cursor, int* __restrict__ bbase,
                       uint2* __restrict__ packedP) {
    __shared__ int sz[256];     // by original k
    __shared__ int ssl[256];    // by slot (sorted size)
    __shared__ int red[256];
    const int t = threadIdx.x;
    sz[t] = (t < ALG_DIM) ? cnt[t] : 0;
    __syncthreads();
    red[t] = sz[t];
    __syncthreads();
    for (int off = 128; off > 0; off >>= 1) {
        if (t < off) red[t] = max(red[t], red[t + off]);
        __syncthreads();
    }
    __shared__ int Ps;
    if (t == 0) {
        int P = (red[0] + 7) & ~7;
        P = max(P, 8);
        P = min(P, PMAX);
        meta[0] = P;
        Ps = P;
    }
    __syncthreads();
    const int stride = Ps + 8;              // per-slot element stride
    int rank = -1, mysz = 0;
    if (t < ALG_DIM) {
        mysz = sz[t];
        rank = 0;
        for (int k = 0; k < ALG_DIM; ++k) {
            int s2 = sz[k];
            rank += (s2 > mysz) || (s2 == mysz && k < t);
        }
        perm[rank]  = t;
        ssz[rank]   = mysz;
        ssl[rank]   = mysz;
        cursor[t]   = rank * stride;
        bbase[t]    = rank * stride;
    }
    __syncthreads();
    if (t < ALG_DIM) {
        // pad my slot: trip = round8(max size in my 16-group, KPB-aligned)
        const int by = rank / KPB;
        const int L  = by * KPB + (((rank - by * KPB) >> 4) << 4);
        const int trip = (ssl[L] + 7) & ~7;
        const int base = rank * stride;
        for (int e = mysz; e < trip + 8; ++e)
            packedP[base + e] = make_uint2(0u, 0u);
    }
}

__global__ void k_scatter(const int* __restrict__ idx_i, const int* __restrict__ idx_j,
                          const int* __restrict__ idx_k, const float* __restrict__ coeff,
                          int* __restrict__ cursor, const int* __restrict__ bbase,
                          uint2* __restrict__ packedP, const int* __restrict__ meta,
                          int nnz) {
    int t = blockIdx.x * blockDim.x + threadIdx.x;
    if (t < nnz) {
        int k = idx_k[t];
        int P = meta[0];
        int pos = atomicAdd(&cursor[k], 1);
        if (pos < bbase[k] + P) {            // can only trip if P was clamped
            const float c = coeff[t];
            H2U hc; hc.h = __builtin_amdgcn_cvt_pkrtz(c, c);
            uint2 p;
            p.x = ((unsigned)idx_i[t] << 4) | ((unsigned)idx_j[t] << 20);
            p.y = hc.u;
            packedP[pos] = p;
        }
    }
}

// ---------- main: plane-layout f16 gather, packed FMA, windowed fp32 flush ----
// 256 threads = 64 streams x 4 lanes over 32 rows x 62 slots. x,y in LDS as
// f16 in 4 planes: (col i, rows 8s..8s+7) at byte s*3984 + i*16. Lane q folds
// q*3984 into its base pointer ONCE; gather = ds_read_b128 at base + i*16,
// whose bank window (i*4 + 4q) mod 32 sweeps all 32 banks as i varies —
// no half-locking (round-5/8 layouts pinned each column to a 16-bank half
// via i&1; the r8 XOR swizzle couldn't fix that and cost 4 VALU/gather).
// Body: 12 VALU/triple (and, shr, 2 add, 4 pk_mul, 4 pk_fma) + 2 b128.
// f16 accumulators flushed to fp32 every 32 triples.

__global__ __launch_bounds__(256, 4) void k_main(
    const float* __restrict__ x, const float* __restrict__ y,
    const uint4* __restrict__ packed4,
    const int* __restrict__ meta, const int* __restrict__ perm,
    const int* __restrict__ ssz,
    const float* __restrict__ alpha_p, float* __restrict__ out)
{
    __shared__ __align__(16) unsigned xs32[4 * PLSTRIDE_DW];
    __shared__ __align__(16) unsigned ys32[4 * PLSTRIDE_DW];

    const int tid = threadIdx.x;
    const int r0  = blockIdx.x * ROWS;

    // Staging: unit u = (row-pair rp 0..15, col-quad cq 0..61). Rows 2rp,2rp+1
    // share plane rp>>2 and dword slot (rp&3) of each column. Store banks:
    // (rp>>2)*4 + (rp&3) + 16*(cq&1) -> 32 distinct banks per store instr.
    for (int u = tid; u < (ALG_DIM / 4) * (ROWS / 2); u += 256) {
        const int rp = u & 15;
        const int cq = u >> 4;
        const size_t ra = (size_t)(r0 + 2 * rp) * ALG_DIM + 4 * cq;
        const float4 xa = *reinterpret_cast<const float4*>(x + ra);
        const float4 xb = *reinterpret_cast<const float4*>(x + ra + ALG_DIM);
        const float4 ya = *reinterpret_cast<const float4*>(y + ra);
        const float4 yb = *reinterpret_cast<const float4*>(y + ra + ALG_DIM);
        const int pbase = (rp >> 2) * PLSTRIDE_DW + (rp & 3);
#define STG(d, XA, XB, YA, YB)                                                  \
        {                                                                       \
            const int dw = pbase + (4 * cq + (d)) * 4;                          \
            H2U hx; hx.h = __builtin_amdgcn_cvt_pkrtz(XA, XB);                  \
            H2U hy; hy.h = __builtin_amdgcn_cvt_pkrtz(YA, YB);                  \
            xs32[dw] = hx.u;                                                    \
            ys32[dw] = hy.u;                                                    \
        }
        STG(0, xa.x, xb.x, ya.x, yb.x)
        STG(1, xa.y, xb.y, ya.y, yb.y)
        STG(2, xa.z, xb.z, ya.z, yb.z)
        STG(3, xa.w, xb.w, ya.w, yb.w)
#undef STG
    }
    __syncthreads();

    const int   P     = meta[0];
    const float alpha = alpha_p[0];
    const int   S     = tid >> 2;            // stream 0..63 (owns one slot)
    const int   q     = tid & 3;             // my plane (rows 8q..8q+7)

    const char* xsb = reinterpret_cast<const char*>(xs32) + q * PLSTRIDE_B;
    const char* ysb = reinterpret_cast<const char*>(ys32) + q * PLSTRIDE_B;

    if (S < KPB) {
        const int p = blockIdx.y * KPB + S;
        const int k = perm[p];

        const int pw   = blockIdx.y * KPB + ((tid >> 6) << 4);
        const int trip = __builtin_amdgcn_readfirstlane((ssz[pw] + 7) & ~7);
        const int nH   = trip >> 1;          // uint4s (2 triples each)

        const uint4* tp = packed4 + (size_t)p * ((size_t)(P + 8) >> 1);

        float a0 = 0.f, a1 = 0.f, a2 = 0.f, a3 = 0.f,
              a4 = 0.f, a5 = 0.f, a6 = 0.f, a7 = 0.f;

        uint4 cur = tp[0];

#define PROC(PW, PC)                                                            \
        {                                                                       \
            const unsigned ox = (PW) & 0xFFFFu;                                 \
            const unsigned oy = (PW) >> 16;                                     \
            const uint4 wx = *reinterpret_cast<const uint4*>(xsb + ox);         \
            const uint4 wy = *reinterpret_cast<const uint4*>(ysb + oy);         \
            H2U cc; cc.u = (PC);                                                \
            H2U ux, uy;                                                         \
            ux.u = wx.x; uy.u = wy.x; c0 = (ux.h * uy.h) * cc.h + c0;           \
            ux.u = wx.y; uy.u = wy.y; c1 = (ux.h * uy.h) * cc.h + c1;           \
            ux.u = wx.z; uy.u = wy.z; c2 = (ux.h * uy.h) * cc.h + c2;           \
            ux.u = wx.w; uy.u = wy.w; c3 = (ux.h * uy.h) * cc.h + c3;           \
        }

        for (int chunk = 0; chunk < nH; chunk += 16) {       // 32-triple window
            h2v c0 = (h2v)0.0f, c1 = (h2v)0.0f, c2 = (h2v)0.0f, c3 = (h2v)0.0f;
            const int hend = min(chunk + 16, nH);
#pragma unroll 2
            for (int h = chunk; h < hend; ++h) {
                const uint4 nxt = tp[h + 1];  // prefetch (pads cover over-read)
                PROC(cur.x, cur.y)
                PROC(cur.z, cur.w)
                cur = nxt;
            }
            a0 += (float)c0.x; a1 += (float)c0.y;
            a2 += (float)c1.x; a3 += (float)c1.y;
            a4 += (float)c2.x; a5 += (float)c2.y;
            a6 += (float)c3.x; a7 += (float)c3.y;
        }
#undef PROC

        const int rbase = r0 + (q << 3);
        out[(size_t)(rbase + 0) * ALG_DIM + k] = alpha * a0;
        out[(size_t)(rbase + 1) * ALG_DIM + k] = alpha * a1;
        out[(size_t)(rbase + 2) * ALG_DIM + k] = alpha * a2;
        out[(size_t)(rbase + 3) * ALG_DIM + k] = alpha * a3;
        out[(size_t)(rbase + 4) * ALG_DIM + k] = alpha * a4;
        out[(size_t)(rbase + 5) * ALG_DIM + k] = alpha * a5;
        out[(size_t)(rbase + 6) * ALG_DIM + k] = alpha * a6;
        out[(size_t)(rbase + 7) * ALG_DIM + k] = alpha * a7;
    }
}

// ---------- launch ----------

extern "C" void kernel_launch(void* const* d_in, const int* in_sizes, int n_in,
                              void* d_out, int out_size, void* d_ws, size_t ws_size,
                              hipStream_t stream) {
    const float* x      = (const float*)d_in[0];
    const float* y      = (const float*)d_in[1];
    const int*   idx_i  = (const int*)d_in[2];
    const int*   idx_j  = (const int*)d_in[3];
    const int*   idx_k  = (const int*)d_in[4];
    const float* coeff  = (const float*)d_in[5];
    const float* alpha  = (const float*)d_in[6];
    float*       out    = (float*)d_out;

    const int nnz   = in_sizes[2];
    const int batch = in_sizes[0] / ALG_DIM;

    // ws: [meta 16B][cnt 1K][cursor 1K][perm 1K][ssz 1K][bbase 1K][pad->8K][packedP]
    char*  ws      = (char*)d_ws;
    int*   meta    = (int*)ws;
    int*   cnt     = (int*)(ws + 16);
    int*   cursor  = (int*)(ws + 16 + 1024);
    int*   perm    = (int*)(ws + 16 + 2 * 1024);
    int*   ssz     = (int*)(ws + 16 + 3 * 1024);
    int*   bbase   = (int*)(ws + 16 + 4 * 1024);
    uint2* packedP = (uint2*)(ws + 8192);

    k_init   <<<1, 256, 0, stream>>>(cnt);
    k_count  <<<(nnz + 255) / 256, 256, 0, stream>>>(idx_k, cnt, nnz);
    k_sort   <<<1, 256, 0, stream>>>(cnt, meta, perm, ssz, cursor, bbase, packedP);
    k_scatter<<<(nnz + 255) / 256, 256, 0, stream>>>(idx_i, idx_j, idx_k, coeff,
                                                     cursor, bbase, packedP, meta, nnz);

    dim3 grid(batch / ROWS, KSPLIT);
    k_main<<<grid, 256, 0, stream>>>(x, y, (const uint4*)packedP, meta, perm, ssz,
                                     alpha, out);
}

// Round 10
// 121.194 us; speedup vs baseline: 3.4244x; 1.2148x over previous
//
#include <hip/hip_runtime.h>

#define ALG_DIM 248
#define ROWS 32                    // rows per main-kernel block
#define KSPLIT 4
#define KPB 62                     // k-slots per block (248/4)
#define PMAX 1024                  // safety clamp for padded bucket length
#define CB 32                      // prep chunk blocks
#define PLSTRIDE_B 3984            // plane stride bytes (248*16 + 16; /4 = 996 ≡ 4 mod 32)
#define PLSTRIDE_DW 996

typedef __fp16 h2v __attribute__((ext_vector_type(2)));
union H2U { unsigned u; h2v h; };

// ---------- prep (4 dispatches, zero global atomics) ----------
// k_hist: 32 blocks, per-block LDS histogram of one nnz/32 chunk -> private
//         global row (full overwrite, no init needed, poison-safe).
// k_sort: one block. Sums rows -> bucket sizes; rank-sorts buckets desc;
//         emits perm/ssz, per-(block,k) scatter cursors coff, limits glim,
//         and writes each slot's zero-pad tail [size, trip+8).
// k_scatter: 32 blocks, same chunking; allocates positions from LDS cursors
//         seeded with coff row -> deterministic, no global atomics.
// packed.x: lo16 = i*16, hi16 = j*16 (within-plane byte offsets).
// packed.y: coeff duplicated as f16x2.

__global__ void k_hist(const int* __restrict__ idx_k, int* __restrict__ hist, int nnz) {
    __shared__ int h[256];
    const int b = blockIdx.x, tid = threadIdx.x;
    h[tid] = 0;
    __syncthreads();
    const int chunk = (nnz + CB - 1) / CB;
    const int lo = b * chunk, hi = min(nnz, lo + chunk);
    for (int t = lo + tid; t < hi; t += 256)
        atomicAdd(&h[idx_k[t]], 1);
    __syncthreads();
    hist[b * 256 + tid] = h[tid];
}

__global__ void k_sort(const int* __restrict__ hist, int* __restrict__ meta,
                       int* __restrict__ perm, int* __restrict__ ssz,
                       int* __restrict__ coff, int* __restrict__ glim,
                       uint2* __restrict__ packedP) {
    __shared__ int sz[256];     // by original k
    __shared__ int ssl[256];    // by slot (sorted size)
    __shared__ int red[256];
    const int t = threadIdx.x;

    int tot = 0;
    for (int b = 0; b < CB; ++b) tot += hist[b * 256 + t];
    sz[t] = (t < ALG_DIM) ? tot : 0;     // rows 248..255 are structurally 0
    __syncthreads();
    red[t] = sz[t];
    __syncthreads();
    for (int off = 128; off > 0; off >>= 1) {
        if (t < off) red[t] = max(red[t], red[t + off]);
        __syncthreads();
    }
    __shared__ int Ps;
    if (t == 0) {
        int P = (red[0] + 7) & ~7;
        P = max(P, 8);
        P = min(P, PMAX);
        meta[0] = P;
        Ps = P;
    }
    __syncthreads();
    const int stride = Ps + 8;           // per-slot element stride

    int rank = 0, mysz = 0;
    if (t < ALG_DIM) {
        mysz = sz[t];
        for (int k = 0; k < ALG_DIM; ++k) {
            int s2 = sz[k];
            rank += (s2 > mysz) || (s2 == mysz && k < t);   // unique ranks
        }
        perm[rank] = t;
        ssz[rank]  = mysz;
        ssl[rank]  = mysz;
        const int base = rank * stride;
        glim[t] = base + Ps;             // overflow limit (only if P clamped)
        int run = base;                  // per-chunk-block cursor starts
        for (int b = 0; b < CB; ++b) {
            coff[b * 256 + t] = run;
            run += hist[b * 256 + t];
        }
    }
    __syncthreads();
    if (t < ALG_DIM) {
        // pad my slot: trip = round8(size of my 16-group's leader slot)
        const int by = rank / KPB;
        const int L  = by * KPB + (((rank - by * KPB) >> 4) << 4);
        const int trip = (ssl[L] + 7) & ~7;
        const int base = rank * stride;
        for (int e = mysz; e < trip + 8; ++e)
            packedP[base + e] = make_uint2(0u, 0u);
    }
}

__global__ void k_scatter(const int* __restrict__ idx_i, const int* __restrict__ idx_j,
                          const int* __restrict__ idx_k, const float* __restrict__ coeff,
                          const int* __restrict__ coff, const int* __restrict__ glim,
                          uint2* __restrict__ packedP, int nnz) {
    __shared__ int cur[256];
    __shared__ int lim[256];
    const int b = blockIdx.x, tid = threadIdx.x;
    cur[tid] = coff[b * 256 + tid];
    lim[tid] = glim[tid];                // k >= 248 rows never referenced
    __syncthreads();
    const int chunk = (nnz + CB - 1) / CB;
    const int lo = b * chunk, hi = min(nnz, lo + chunk);
    for (int t = lo + tid; t < hi; t += 256) {
        const int k = idx_k[t];
        const int pos = atomicAdd(&cur[k], 1);      // LDS atomic only
        if (pos < lim[k]) {
            const float c = coeff[t];
            H2U hc; hc.h = __builtin_amdgcn_cvt_pkrtz(c, c);
            uint2 p;
            p.x = ((unsigned)idx_i[t] << 4) | ((unsigned)idx_j[t] << 20);
            p.y = hc.u;
            packedP[pos] = p;
        }
    }
}

// ---------- main: plane-layout f16 gather, packed FMA, windowed fp32 flush ----
// (unchanged from round 9 — at its LDS-bound floor)
// 256 threads = 64 streams x 4 lanes over 32 rows x 62 slots. x,y in LDS as
// f16 in 4 planes: (col i, rows 8s..8s+7) at byte s*3984 + i*16. Lane q folds
// q*3984 into its base pointer once; gather = ds_read_b128 at base + i*16,
// bank window (i*4 + 4q) mod 32 sweeps all 32 banks as i varies.
// Body: 12 VALU/triple + 2 b128. f16 accs flushed to fp32 every 32 triples.

__global__ __launch_bounds__(256, 4) void k_main(
    const float* __restrict__ x, const float* __restrict__ y,
    const uint4* __restrict__ packed4,
    const int* __restrict__ meta, const int* __restrict__ perm,
    const int* __restrict__ ssz,
    const float* __restrict__ alpha_p, float* __restrict__ out)
{
    __shared__ __align__(16) unsigned xs32[4 * PLSTRIDE_DW];
    __shared__ __align__(16) unsigned ys32[4 * PLSTRIDE_DW];

    const int tid = threadIdx.x;
    const int r0  = blockIdx.x * ROWS;

    for (int u = tid; u < (ALG_DIM / 4) * (ROWS / 2); u += 256) {
        const int rp = u & 15;
        const int cq = u >> 4;
        const size_t ra = (size_t)(r0 + 2 * rp) * ALG_DIM + 4 * cq;
        const float4 xa = *reinterpret_cast<const float4*>(x + ra);
        const float4 xb = *reinterpret_cast<const float4*>(x + ra + ALG_DIM);
        const float4 ya = *reinterpret_cast<const float4*>(y + ra);
        const float4 yb = *reinterpret_cast<const float4*>(y + ra + ALG_DIM);
        const int pbase = (rp >> 2) * PLSTRIDE_DW + (rp & 3);
#define STG(d, XA, XB, YA, YB)                                                  \
        {                                                                       \
            const int dw = pbase + (4 * cq + (d)) * 4;                          \
            H2U hx; hx.h = __builtin_amdgcn_cvt_pkrtz(XA, XB);                  \
            H2U hy; hy.h = __builtin_amdgcn_cvt_pkrtz(YA, YB);                  \
            xs32[dw] = hx.u;                                                    \
            ys32[dw] = hy.u;                                                    \
        }
        STG(0, xa.x, xb.x, ya.x, yb.x)
        STG(1, xa.y, xb.y, ya.y, yb.y)
        STG(2, xa.z, xb.z, ya.z, yb.z)
        STG(3, xa.w, xb.w, ya.w, yb.w)
#undef STG
    }
    __syncthreads();

    const int   P     = meta[0];
    const float alpha = alpha_p[0];
    const int   S     = tid >> 2;            // stream 0..63 (owns one slot)
    const int   q     = tid & 3;             // my plane (rows 8q..8q+7)

    const char* xsb = reinterpret_cast<const char*>(xs32) + q * PLSTRIDE_B;
    const char* ysb = reinterpret_cast<const char*>(ys32) + q * PLSTRIDE_B;

    if (S < KPB) {
        const int p = blockIdx.y * KPB + S;
        const int k = perm[p];

        const int pw   = blockIdx.y * KPB + ((tid >> 6) << 4);
        const int trip = __builtin_amdgcn_readfirstlane((ssz[pw] + 7) & ~7);
        const int nH   = trip >> 1;          // uint4s (2 triples each)

        const uint4* tp = packed4 + (size_t)p * ((size_t)(P + 8) >> 1);

        float a0 = 0.f, a1 = 0.f, a2 = 0.f, a3 = 0.f,
              a4 = 0.f, a5 = 0.f, a6 = 0.f, a7 = 0.f;

        uint4 cur = tp[0];

#define PROC(PW, PC)                                                            \
        {                                                                       \
            const unsigned ox = (PW) & 0xFFFFu;                                 \
            const unsigned oy = (PW) >> 16;                                     \
            const uint4 wx = *reinterpret_cast<const uint4*>(xsb + ox);         \
            const uint4 wy = *reinterpret_cast<const uint4*>(ysb + oy);         \
            H2U cc; cc.u = (PC);                                                \
            H2U ux, uy;                                                         \
            ux.u = wx.x; uy.u = wy.x; c0 = (ux.h * uy.h) * cc.h + c0;           \
            ux.u = wx.y; uy.u = wy.y; c1 = (ux.h * uy.h) * cc.h + c1;           \
            ux.u = wx.z; uy.u = wy.z; c2 = (ux.h * uy.h) * cc.h + c2;           \
            ux.u = wx.w; uy.u = wy.w; c3 = (ux.h * uy.h) * cc.h + c3;           \
        }

        for (int chunk = 0; chunk < nH; chunk += 16) {       // 32-triple window
            h2v c0 = (h2v)0.0f, c1 = (h2v)0.0f, c2 = (h2v)0.0f, c3 = (h2v)0.0f;
            const int hend = min(chunk + 16, nH);
#pragma unroll 2
            for (int h = chunk; h < hend; ++h) {
                const uint4 nxt = tp[h + 1];  // prefetch (pads cover over-read)
                PROC(cur.x, cur.y)
                PROC(cur.z, cur.w)
                cur = nxt;
            }
            a0 += (float)c0.x; a1 += (float)c0.y;
            a2 += (float)c1.x; a3 += (float)c1.y;
            a4 += (float)c2.x; a5 += (float)c2.y;
            a6 += (float)c3.x; a7 += (float)c3.y;
        }
#undef PROC

        const int rbase = r0 + (q << 3);
        out[(size_t)(rbase + 0) * ALG_DIM + k] = alpha * a0;
        out[(size_t)(rbase + 1) * ALG_DIM + k] = alpha * a1;
        out[(size_t)(rbase + 2) * ALG_DIM + k] = alpha * a2;
        out[(size_t)(rbase + 3) * ALG_DIM + k] = alpha * a3;
        out[(size_t)(rbase + 4) * ALG_DIM + k] = alpha * a4;
        out[(size_t)(rbase + 5) * ALG_DIM + k] = alpha * a5;
        out[(size_t)(rbase + 6) * ALG_DIM + k] = alpha * a6;
        out[(size_t)(rbase + 7) * ALG_DIM + k] = alpha * a7;
    }
}

// ---------- launch ----------

extern "C" void kernel_launch(void* const* d_in, const int* in_sizes, int n_in,
                              void* d_out, int out_size, void* d_ws, size_t ws_size,
                              hipStream_t stream) {
    const float* x      = (const float*)d_in[0];
    const float* y      = (const float*)d_in[1];
    const int*   idx_i  = (const int*)d_in[2];
    const int*   idx_j  = (const int*)d_in[3];
    const int*   idx_k  = (const int*)d_in[4];
    const float* coeff  = (const float*)d_in[5];
    const float* alpha  = (const float*)d_in[6];
    float*       out    = (float*)d_out;

    const int nnz   = in_sizes[2];
    const int batch = in_sizes[0] / ALG_DIM;

    // ws: [meta @0][perm @1K][ssz @2K][glim @3K][hist @4K, 32K][coff @36864, 32K][packedP @69632]
    char*  ws      = (char*)d_ws;
    int*   meta    = (int*)ws;
    int*   perm    = (int*)(ws + 1024);
    int*   ssz     = (int*)(ws + 2048);
    int*   glim    = (int*)(ws + 3072);
    int*   hist    = (int*)(ws + 4096);
    int*   coff    = (int*)(ws + 4096 + CB * 256 * 4);
    uint2* packedP = (uint2*)(ws + 4096 + 2 * CB * 256 * 4 + 1024);

    k_hist   <<<CB, 256, 0, stream>>>(idx_k, hist, nnz);
    k_sort   <<<1, 256, 0, stream>>>(hist, meta, perm, ssz, coff, glim, packedP);
    k_scatter<<<CB, 256, 0, stream>>>(idx_i, idx_j, idx_k, coeff, coff, glim,
                                      packedP, nnz);

    dim3 grid(batch / ROWS, KSPLIT);
    k_main<<<grid, 256, 0, stream>>>(x, y, (const uint4*)packedP, meta, perm, ssz,
                                     alpha, out);
}